// Round 8
// baseline (252.451 us; speedup 1.0000x reference)
//
#include <hip/hip_runtime.h>

#define NN   6
#define H1   64
#define H2   512
#define H3   256
#define TM   128
#define KC   16
#define NCH  (H2 / KC)    // 32 chunks

typedef short s16x8 __attribute__((ext_vector_type(8)));
typedef float f32x16 __attribute__((ext_vector_type(16)));
typedef float f32x4v __attribute__((ext_vector_type(4)));
typedef unsigned int u32x4 __attribute__((ext_vector_type(4)));

__device__ __forceinline__ unsigned int cvt_pk_bf16(float a, float b) {
    unsigned int r;
    asm("v_cvt_pk_bf16_f32 %0, %1, %2" : "=v"(r) : "v"(a), "v"(b));
    return r;
}
__device__ __forceinline__ void g2lds16(const void* g, void* l) {
    __builtin_amdgcn_global_load_lds(
        (const __attribute__((address_space(1))) unsigned int*)g,
        (__attribute__((address_space(3))) unsigned int*)l, 16, 0, 0);
}

// Single fused kernel, wave-specialized:
//   waves 0-3 (producers): stage raw Wl2 f32 chunks (g2lds), split W -> hi/lo
//     bf16 in LDS, generate x1 A-fragments (hi/lo) in LDS. All VALU/VMEM.
//   waves 4-7 (consumers): pure MFMA (24 per chunk each) + frag ds_reads.
// Per SIMD: 1 producer + 1 consumer wave -> m114-style pipe overlap.
__global__ __launch_bounds__(512, 2)
void gcn_fused(const float* __restrict__ f,    // [6][B]
               const float* __restrict__ W0,   // [64]
               const float* __restrict__ b0,   // [64]
               const float* __restrict__ W1,   // [64]
               const float* __restrict__ b1_,  // [1]
               const float* __restrict__ Wl0,  // [6][512]
               const float* __restrict__ bl0,  // [512]
               const float* __restrict__ Wl2,  // [512][256] raw f32
               const float* __restrict__ bl2,  // [256]
               const float* __restrict__ Wl3,  // [256]
               const float* __restrict__ bl3_, // [1]
               float* __restrict__ out,        // [B]
               int B)
{
    __shared__ float sW0[H1], sB0[H1], sW1[H1];
    __shared__ float sWl0[NN][H2];
    __shared__ float sBl0[H2];
    __shared__ float sBl2[H3];
    __shared__ float sWl3[H3];
    __shared__ float sF[NN][TM];             // reused as sRed[4][128] in epilogue
    __shared__ float sS[NN][TM];
    __shared__ float sX[NN][TM];
    __shared__ __align__(16) float sWf[2][4096];          // raw W chunks (2x16KB)
    __shared__ __align__(16) unsigned short sA[8192];     // [buf2][p2][oct2][row128][j8]
    __shared__ __align__(16) unsigned short sB[2][8192];  // [buf][p][oct2][col256][j8]

    const int t    = threadIdx.x;
    const int lane = t & 63;
    const int w    = t >> 6;        // wave 0..7
    const int cl   = lane & 31;
    const int h    = lane >> 5;     // k-octet selector
    const int m0   = blockIdx.x * TM;
    const bool prod = (w < 4);

    // ---- stage small weights + input tile (all waves) ----
    for (int i = t; i < H1; i += 512) { sW0[i] = W0[i]; sB0[i] = b0[i]; sW1[i] = W1[i]; }
    for (int i = t; i < NN * H2; i += 512) sWl0[i >> 9][i & (H2 - 1)] = Wl0[i];
    for (int i = t; i < H2; i += 512) sBl0[i] = bl0[i];
    for (int i = t; i < H3; i += 512) { sBl2[i] = bl2[i]; sWl3[i] = Wl3[i]; }
    for (int i = t; i < NN * TM; i += 512) sF[i >> 7][i & (TM - 1)] = f[(i >> 7) * B + m0 + (i & (TM - 1))];

    // stage raw W chunk CH (16 KiB) into sWf[BUF]; producers only (w<4)
#define STAGE_WF(CH, BUF) do {                                                     \
        const char* _s = (const char*)Wl2 + (CH) * 16384 + (w << 12) + (lane << 4);\
        char*       _d = (char*)&sWf[BUF][0] + (w << 12);                          \
        _Pragma("unroll")                                                          \
        for (int _q = 0; _q < 4; ++_q) g2lds16(_s + (_q << 10), _d + (_q << 10));  \
    } while (0)

    if (prod) { STAGE_WF(0, 0); STAGE_WF(1, 1); }
    __syncthreads();   // sF + wf0/wf1 ready

    const float b1v = b1_[0];

    // ---- graph convs collapsed to scalar recurrences (ring, deg=2) ----
    for (int v = t; v < NN * TM; v += 512) {
        const int i = v >> 7, r = v & (TM - 1);
        const int im = (i + NN - 1) % NN, ip = (i + 1) % NN;
        const float g = 0.5f * (sF[im][r] + sF[ip][r]);
        float s = 0.f;
        #pragma unroll
        for (int c = 0; c < H1; ++c) {
            float hx = g * sW0[c] + sB0[c];
            hx = fmaxf(hx, 0.01f * hx);
            s += hx * sW1[c];
        }
        sS[i][r] = s;
    }
    __syncthreads();
    for (int v = t; v < NN * TM; v += 512) {
        const int i = v >> 7, r = v & (TM - 1);
        const int im = (i + NN - 1) % NN, ip = (i + 1) % NN;
        const float xv = 0.5f * (sS[im][r] + sS[ip][r]) + b1v;
        sX[i][r] = fmaxf(xv, 0.01f * xv);
    }
    __syncthreads();

    // split raw W chunk in sWf[SRCBUF] -> hi/lo bf16 in sB[DSTBUF]
    // prod lane owns col = w*64+lane, both k-octets
#define SPLIT_W(SRCBUF, DSTBUF) do {                                               \
        const int _col = (w << 6) + lane;                                          \
        _Pragma("unroll")                                                          \
        for (int _o = 0; _o < 2; ++_o) {                                           \
            float _v[8];                                                           \
            _Pragma("unroll")                                                      \
            for (int _j = 0; _j < 8; ++_j)                                         \
                _v[_j] = sWf[SRCBUF][(((_o << 3) + _j) << 8) + _col];              \
            unsigned int _hi[4], _lo[4];                                           \
            _Pragma("unroll")                                                      \
            for (int _p = 0; _p < 4; ++_p) {                                       \
                const unsigned int _uh = cvt_pk_bf16(_v[2*_p], _v[2*_p+1]);        \
                const float _h0 = __uint_as_float(_uh << 16);                      \
                const float _h1 = __uint_as_float(_uh & 0xFFFF0000u);              \
                _hi[_p] = _uh;                                                     \
                _lo[_p] = cvt_pk_bf16(_v[2*_p] - _h0, _v[2*_p+1] - _h1);           \
            }                                                                      \
            *(u32x4*)&sB[DSTBUF][(_o << 11) + (_col << 3)] =                       \
                (u32x4){_hi[0], _hi[1], _hi[2], _hi[3]};                           \
            *(u32x4*)&sB[DSTBUF][4096 + (_o << 11) + (_col << 3)] =                \
                (u32x4){_lo[0], _lo[1], _lo[2], _lo[3]};                           \
        }                                                                          \
    } while (0)

    // generate A (x1 hi/lo) for chunk CH into sA buf BUF; lane owns (prow, poct)
#define GEN_A(CH, BUF) do {                                                        \
        const int _k0 = ((CH) << 4) + (poct << 3);                                 \
        f32x4v _za = *(const f32x4v*)&sBl0[_k0];                                   \
        f32x4v _zb = *(const f32x4v*)&sBl0[_k0 + 4];                               \
        _Pragma("unroll")                                                          \
        for (int _i = 0; _i < 6; ++_i) {                                           \
            const f32x4v _wa = *(const f32x4v*)&sWl0[_i][_k0];                     \
            const f32x4v _wb = *(const f32x4v*)&sWl0[_i][_k0 + 4];                 \
            _za += xr[_i] * _wa;                                                   \
            _zb += xr[_i] * _wb;                                                   \
        }                                                                          \
        _za = __builtin_elementwise_max(_za, 0.01f * _za);                         \
        _zb = __builtin_elementwise_max(_zb, 0.01f * _zb);                         \
        const float _vv[8] = {_za[0],_za[1],_za[2],_za[3],_zb[0],_zb[1],_zb[2],_zb[3]}; \
        unsigned int _hi[4], _lo[4];                                               \
        _Pragma("unroll")                                                          \
        for (int _p = 0; _p < 4; ++_p) {                                           \
            const unsigned int _uh = cvt_pk_bf16(_vv[2*_p], _vv[2*_p+1]);          \
            const float _h0 = __uint_as_float(_uh << 16);                          \
            const float _h1 = __uint_as_float(_uh & 0xFFFF0000u);                  \
            _hi[_p] = _uh;                                                         \
            _lo[_p] = cvt_pk_bf16(_vv[2*_p] - _h0, _vv[2*_p+1] - _h1);             \
        }                                                                          \
        *(u32x4*)&sA[((((BUF) << 2) + poct) << 10) + (prow << 3)] =                \
            (u32x4){_hi[0], _hi[1], _hi[2], _hi[3]};                               \
        *(u32x4*)&sA[((((BUF) << 2) + 2 + poct) << 10) + (prow << 3)] =            \
            (u32x4){_lo[0], _lo[1], _lo[2], _lo[3]};                               \
    } while (0)

    // consumer: read frags for buf BUF, 24 MFMAs (4 row-tiles x 2 col-tiles x 3 passes)
#define CONS_WIN(BUF) do {                                                         \
        s16x8 _ah[4], _al[4], _bh[2], _bl[2];                                      \
        const int _ab = ((((BUF) << 2) + h) << 10) + (cl << 3);                    \
        _Pragma("unroll")                                                          \
        for (int _rt = 0; _rt < 4; ++_rt) {                                        \
            _ah[_rt] = *(const s16x8*)&sA[_ab + (_rt << 8)];                       \
            _al[_rt] = *(const s16x8*)&sA[_ab + 2048 + (_rt << 8)];                \
        }                                                                          \
        const int _bb = (h << 11) + (((wc2 << 6) + cl) << 3);                      \
        _Pragma("unroll")                                                          \
        for (int _g = 0; _g < 2; ++_g) {                                           \
            _bh[_g] = *(const s16x8*)&sB[BUF][_bb + (_g << 8)];                    \
            _bl[_g] = *(const s16x8*)&sB[BUF][4096 + _bb + (_g << 8)];             \
        }                                                                          \
        _Pragma("unroll")                                                          \
        for (int _rt = 0; _rt < 4; ++_rt)                                          \
            _Pragma("unroll")                                                      \
            for (int _g = 0; _g < 2; ++_g)                                         \
                acc[_rt][_g] = __builtin_amdgcn_mfma_f32_32x32x16_bf16(_ah[_rt], _bh[_g], acc[_rt][_g], 0, 0, 0); \
        _Pragma("unroll")                                                          \
        for (int _rt = 0; _rt < 4; ++_rt)                                          \
            _Pragma("unroll")                                                      \
            for (int _g = 0; _g < 2; ++_g)                                         \
                acc[_rt][_g] = __builtin_amdgcn_mfma_f32_32x32x16_bf16(_al[_rt], _bh[_g], acc[_rt][_g], 0, 0, 0); \
        _Pragma("unroll")                                                          \
        for (int _rt = 0; _rt < 4; ++_rt)                                          \
            _Pragma("unroll")                                                      \
            for (int _g = 0; _g < 2; ++_g)                                         \
                acc[_rt][_g] = __builtin_amdgcn_mfma_f32_32x32x16_bf16(_ah[_rt], _bl[_g], acc[_rt][_g], 0, 0, 0); \
    } while (0)

    float xr[NN];
    int poct = 0, prow = 0, wc2 = 0;
    f32x16 acc[4][2];

    if (prod) {
        poct = w >> 1;                       // waves 0,1 -> oct 0; 2,3 -> oct 1
        prow = ((w & 1) << 6) + lane;        // 64 rows per wave
        #pragma unroll
        for (int i = 0; i < NN; ++i) xr[i] = sX[i][prow];
        SPLIT_W(0, 0);                       // chunk 0: wf0 -> sB0
        GEN_A(0, 0);                         // A(0) -> sA buf0
    } else {
        wc2 = w - 4;                         // consumer col-group: 64 cols each
        #pragma unroll
        for (int rt = 0; rt < 4; ++rt)
            #pragma unroll
            for (int g = 0; g < 2; ++g)
                #pragma unroll
                for (int rg = 0; rg < 16; ++rg) acc[rt][g][rg] = 0.f;
    }
    __syncthreads();   // sA0 / sB0 ready

    // ---- main loop: 32 chunk windows, unrolled x2 for static buffers ----
    for (int ch = 0; ch < NCH; ch += 2) {
        // window ch: consume buf0; prep chunk ch+1 (wf1 -> sB1, A -> sA1); stage ch+2 -> wf0
        if (prod) {
            if (ch + 2 < NCH) STAGE_WF(ch + 2, 0);
            SPLIT_W(1, 1);
            GEN_A(ch + 1, 1);
        } else {
            CONS_WIN(0);
        }
        __syncthreads();
        // window ch+1: consume buf1; prep chunk ch+2 (wf0 -> sB0, A -> sA0); stage ch+3 -> wf1
        if (prod) {
            if (ch + 3 < NCH) STAGE_WF(ch + 3, 1);
            if (ch + 2 < NCH) { SPLIT_W(0, 0); GEN_A(ch + 2, 0); }
        } else {
            CONS_WIN(1);
        }
        __syncthreads();
    }

    // ---- epilogue: consumers reduce their 64-col slice, then block-combine ----
    float* sRed = &sF[0][0];     // [4][128]
    if (!prod) {
        float ps[4][16];
        #pragma unroll
        for (int rt = 0; rt < 4; ++rt)
            #pragma unroll
            for (int rg = 0; rg < 16; ++rg) ps[rt][rg] = 0.f;
        #pragma unroll
        for (int g = 0; g < 2; ++g) {
            const int col = (wc2 << 6) + (g << 5) + cl;
            const float b2 = sBl2[col], w3 = sWl3[col];
            #pragma unroll
            for (int rt = 0; rt < 4; ++rt)
                #pragma unroll
                for (int rg = 0; rg < 16; ++rg) {
                    float v = acc[rt][g][rg] + b2;
                    v = fmaxf(v, 0.01f * v);
                    ps[rt][rg] += v * w3;
                }
        }
        #pragma unroll
        for (int msk = 1; msk < 32; msk <<= 1)
            #pragma unroll
            for (int rt = 0; rt < 4; ++rt)
                #pragma unroll
                for (int rg = 0; rg < 16; ++rg) ps[rt][rg] += __shfl_xor(ps[rt][rg], msk);
        if (cl == 0) {
            #pragma unroll
            for (int rt = 0; rt < 4; ++rt)
                #pragma unroll
                for (int rg = 0; rg < 16; ++rg) {
                    const int row = (rt << 5) + (rg & 3) + ((rg >> 2) << 3) + (h << 2);
                    sRed[(wc2 << 7) + row] = ps[rt][rg];
                }
        }
    }
    __syncthreads();
    if (t < TM) {
        const float bl3v = bl3_[0];
        const float v = sRed[t] + sRed[TM + t] + sRed[2 * TM + t] + sRed[3 * TM + t] + bl3v;
        out[m0 + t] = fmaxf(v, 0.01f * v);
    }
}

extern "C" void kernel_launch(void* const* d_in, const int* in_sizes, int n_in,
                              void* d_out, int out_size, void* d_ws, size_t ws_size,
                              hipStream_t stream) {
    const float* f   = (const float*)d_in[0];
    const float* W0  = (const float*)d_in[3];
    const float* b0  = (const float*)d_in[4];
    const float* W1  = (const float*)d_in[5];
    const float* b1  = (const float*)d_in[6];
    const float* Wl0 = (const float*)d_in[7];
    const float* bl0 = (const float*)d_in[8];
    const float* Wl2 = (const float*)d_in[9];
    const float* bl2 = (const float*)d_in[10];
    const float* Wl3 = (const float*)d_in[11];
    const float* bl3 = (const float*)d_in[12];
    float* out = (float*)d_out;
    const int B = in_sizes[0] / NN;

    gcn_fused<<<dim3(B / TM), 512, 0, stream>>>(f, W0, b0, W1, b1, Wl0, bl0,
                                                Wl2, bl2, Wl3, bl3, out, B);
}